// Round 7
// baseline (3258.445 us; speedup 1.0000x reference)
//
#include <hip/hip_runtime.h>

#define NNODES 100000
#define NEDGES 300000
#define KF     1433
#define KP     1536   // 24*64, zero-padded tail
#define HID    16
#define NC     7
#define ROWS   8                 // rows per wave-group (round-1 proven shape)
#define NGRP   (NNODES / ROWS)   // 12500 groups, exact
#define NITK   23                // ceil(1433/64)

// ---------------------------------------------------------------------------
// Kernel A: y = x @ w1 (fp32 end-to-end), agg = (1+eps)*y.
// Round-1 proven structure: 512 threads, 256 blocks, fp32 W1^T in LDS (96 KB,
// 1 block/CU, 2 waves/SIMD). Added vs round 1: depth-2 register prefetch
// (xa/xb) for ILP latency hiding, and contiguous balanced row chunks.
// CONSTRAINTS LEARNED:
//  - W1 must be fp32: eps=100 makes agg=(101)*y + sum, amplifying any W1
//    quantization error 101x (round 6: bf16 W1 -> absmax 0.055 > 0.02).
//  - 1024-thread blocks: allocator pins VGPR=64 -> spill (rounds 2-4).
//  - K-split across blocks: segmented row reads -> 4.4x overfetch (round 5).
// VGPR: acc[8][16]=128 + xa/xb 16 + addr ~30 => ~175 < 256 (2 waves/SIMD ok).
// ---------------------------------------------------------------------------
__global__ __launch_bounds__(512) void gemm_xw1(const float* __restrict__ x,
                                                const float* __restrict__ w1,
                                                const float* __restrict__ epsp,
                                                float* __restrict__ y,
                                                float* __restrict__ agg) {
    __shared__ float w1t[HID * KP];  // [j][k], 96 KB

    const int tid = threadIdx.x;

    // Stage w1 transposed + zero-pad k in [KF, KP)
    for (int k0 = tid; k0 < KP; k0 += 512) {
        if (k0 < KF) {
            const float4* w4 = (const float4*)(w1 + (size_t)k0 * HID);
            const float4 a = w4[0], b = w4[1], c = w4[2], d = w4[3];
            w1t[ 0*KP+k0]=a.x; w1t[ 1*KP+k0]=a.y; w1t[ 2*KP+k0]=a.z; w1t[ 3*KP+k0]=a.w;
            w1t[ 4*KP+k0]=b.x; w1t[ 5*KP+k0]=b.y; w1t[ 6*KP+k0]=b.z; w1t[ 7*KP+k0]=b.w;
            w1t[ 8*KP+k0]=c.x; w1t[ 9*KP+k0]=c.y; w1t[10*KP+k0]=c.z; w1t[11*KP+k0]=c.w;
            w1t[12*KP+k0]=d.x; w1t[13*KP+k0]=d.y; w1t[14*KP+k0]=d.z; w1t[15*KP+k0]=d.w;
        } else {
            #pragma unroll
            for (int j = 0; j < HID; ++j) w1t[j * KP + k0] = 0.f;
        }
    }
    __syncthreads();

    const int lane = tid & 63;
    const int wid  = blockIdx.x * 8 + (tid >> 6);    // 2048 waves
    const float co = 1.f + epsp[0];
    // element kept by lane after the 4 halving steps: bitrev4(lane&15)
    const int jout = ((lane & 1) << 3) | ((lane & 2) << 1) | ((lane & 4) >> 1) | ((lane & 8) >> 3);

    // contiguous, balanced group range for this wave (2048 waves, 12500 groups)
    const int g0 = (int)(((long long)wid       * NGRP) >> 11);
    const int g1 = (int)(((long long)(wid + 1) * NGRP) >> 11);

    for (int g = g0; g < g1; ++g) {
        const int base = g * ROWS;
        const float* px = x + (size_t)base * KF;

        float acc[ROWS][HID];
        #pragma unroll
        for (int r = 0; r < ROWS; ++r)
            #pragma unroll
            for (int j = 0; j < HID; ++j) acc[r][j] = 0.f;

        float xa[ROWS], xb[ROWS];

        auto ld = [&](float* dst, int it) {
            const int k = lane + it * 64;
            #pragma unroll
            for (int r = 0; r < ROWS; ++r)
                dst[r] = (k < KF) ? px[(size_t)r * KF + k] : 0.f;
        };
        auto fmab = [&](const float* xv, int it) {
            const int k = lane + it * 64;
            #pragma unroll
            for (int j = 0; j < HID; ++j) {
                const float wv = w1t[j * KP + k];   // zero-filled beyond KF
                #pragma unroll
                for (int r = 0; r < ROWS; ++r) acc[r][j] += xv[r] * wv;
            }
        };

        ld(xa, 0);
        ld(xb, 1);
        for (int it = 0; it < 22; it += 2) {
            fmab(xa, it);     ld(xa, it + 2);   // it+2 <= 22
            fmab(xb, it + 1); ld(xb, it + 3);   // it+3 <= 23 (guarded -> zeros)
        }
        fmab(xa, 22);   // it=23 contributes nothing (x loaded as 0)

        // Halving transpose-reduce: 16 vals x 64 lanes -> lane jout holds col sum
        #pragma unroll
        for (int r = 0; r < ROWS; ++r) {
            float v[HID];
            #pragma unroll
            for (int j = 0; j < HID; ++j) v[j] = acc[r][j];
            #pragma unroll
            for (int s = 0; s < 4; ++s) {
                const int d    = 1 << s;
                const int half = 8 >> s;
                const int sel  = (lane >> s) & 1;
                #pragma unroll
                for (int m = 0; m < half; ++m) {
                    const float send = sel ? v[m] : v[m + half];
                    const float keep = sel ? v[m + half] : v[m];
                    v[m] = keep + __shfl_xor(send, d);
                }
            }
            float t = v[0];
            t += __shfl_xor(t, 16);
            t += __shfl_xor(t, 32);
            if (lane < HID) {
                const size_t o = (size_t)(base + r) * HID + jout;
                y[o]   = t;
                agg[o] = co * t;   // (1+eps)*y folded in; scatter adds on top
            }
        }
    }
}

// ---------------------------------------------------------------------------
// Kernel B: agg[dst] += y[src]  (thread per (edge, j))
// ---------------------------------------------------------------------------
__global__ __launch_bounds__(256) void scatter_add(const int* __restrict__ ei,
                                                   const float* __restrict__ y,
                                                   float* __restrict__ agg) {
    const int t = blockIdx.x * 256 + threadIdx.x;
    const int e = t >> 4;
    const int j = t & 15;
    if (e < NEDGES) {
        const int s = ei[e];           // src
        const int d = ei[NEDGES + e];  // dst
        atomicAdd(agg + d * HID + j, y[s * HID + j]);
    }
}

// ---------------------------------------------------------------------------
// Kernel C: out = sigmoid(relu(agg + b1) @ w2 + b2)   (agg already has eps term)
// ---------------------------------------------------------------------------
__global__ __launch_bounds__(256) void mlp_tail(const float* __restrict__ agg,
                                                const float* __restrict__ b1,
                                                const float* __restrict__ w2,
                                                const float* __restrict__ b2,
                                                float* __restrict__ out) {
    __shared__ float sw2[HID * NC];
    __shared__ float sb1[HID];
    __shared__ float sb2[NC];

    const int t = threadIdx.x;
    if (t < HID * NC) sw2[t] = w2[t];
    if (t < HID)      sb1[t] = b1[t];
    if (t < NC)       sb2[t] = b2[t];
    __syncthreads();

    const int i = blockIdx.x * 256 + t;
    if (i >= NNODES) return;

    const float4* a4 = (const float4*)(agg + i * HID);

    float h[HID];
    #pragma unroll
    for (int q = 0; q < 4; ++q) {
        const float4 av = a4[q];
        h[q * 4 + 0] = fmaxf(av.x + sb1[q * 4 + 0], 0.f);
        h[q * 4 + 1] = fmaxf(av.y + sb1[q * 4 + 1], 0.f);
        h[q * 4 + 2] = fmaxf(av.z + sb1[q * 4 + 2], 0.f);
        h[q * 4 + 3] = fmaxf(av.w + sb1[q * 4 + 3], 0.f);
    }

    #pragma unroll
    for (int c = 0; c < NC; ++c) {
        float s = sb2[c];
        #pragma unroll
        for (int j = 0; j < HID; ++j) s += h[j] * sw2[j * NC + c];
        out[i * NC + c] = 1.f / (1.f + __expf(-s));
    }
}

// ---------------------------------------------------------------------------
extern "C" void kernel_launch(void* const* d_in, const int* in_sizes, int n_in,
                              void* d_out, int out_size, void* d_ws, size_t ws_size,
                              hipStream_t stream) {
    const float* x   = (const float*)d_in[0];
    const int*   ei  = (const int*)d_in[1];
    const float* w1  = (const float*)d_in[2];
    const float* b1  = (const float*)d_in[3];
    const float* w2  = (const float*)d_in[4];
    const float* b2  = (const float*)d_in[5];
    const float* eps = (const float*)d_in[6];
    float* out = (float*)d_out;

    const size_t NY = (size_t)NNODES * HID;
    float* y   = (float*)d_ws;   // 6.4 MB
    float* agg = y + NY;         // 6.4 MB

    gemm_xw1<<<256, 512, 0, stream>>>(x, w1, eps, y, agg);
    scatter_add<<<(NEDGES * 16 + 255) / 256, 256, 0, stream>>>(ei, y, agg);
    mlp_tail<<<(NNODES + 255) / 256, 256, 0, stream>>>(agg, b1, w2, b2, out);
}

// Round 8
// 383.357 us; speedup vs baseline: 8.4998x; 8.4998x over previous
//
#include <hip/hip_runtime.h>

#define NNODES 100000
#define NEDGES 300000
#define KF     1433
#define KP     1536   // 24*64, zero-padded tail
#define HID    16
#define NC     7

// ---------------------------------------------------------------------------
// Kernel A: y = x @ w1 (fp32), agg = (1+eps)*y.  VERBATIM round-1 structure:
// 512 threads, 256 blocks, fp32 W1^T in LDS (96 KB), serial ld->fma inner
// loop, strided 64-row passes.  Round 1 = the only non-spilling fast config
// (277 us total).  Only deltas: halving-reduce epilogue (proven rounds 5-7,
// 6x less shuffle VALU) and agg=(1+eps)*y fold (kills zero_agg + tail read).
// DO NOT add register prefetch here: round 7 (xa/xb dbuf) pushed live range
// past the allocator's 128-VGPR heuristic -> acc spilled -> 5.5 GB traffic.
// DO NOT use 1024-thr blocks (VGPR pinned 64, rounds 2-4) or K-split blocks
// (4.4x overfetch, round 5) or bf16 W1 (eps=100 amplifies quant error 101x,
// round 6).
// ---------------------------------------------------------------------------
__global__ __launch_bounds__(512) void gemm_xw1(const float* __restrict__ x,
                                                const float* __restrict__ w1,
                                                const float* __restrict__ epsp,
                                                float* __restrict__ y,
                                                float* __restrict__ agg) {
    __shared__ float w1t[HID * KP];  // [j][k], 96 KB

    const int tid = threadIdx.x;

    // Stage w1 transposed + zero-pad k in [KF, KP)
    for (int k = tid; k < KP; k += 512) {
        if (k < KF) {
            const float* r = w1 + k * HID;
            #pragma unroll
            for (int j = 0; j < HID; ++j) w1t[j * KP + k] = r[j];
        } else {
            #pragma unroll
            for (int j = 0; j < HID; ++j) w1t[j * KP + k] = 0.f;
        }
    }
    __syncthreads();

    const int wave = tid >> 6;
    const int lane = tid & 63;
    const float co = 1.f + epsp[0];
    // element kept by lane after the 4 halving steps: bitrev4(lane&15)
    const int jout = ((lane & 1) << 3) | ((lane & 2) << 1) | ((lane & 4) >> 1) | ((lane & 8) >> 3);

    // round-1 iteration pattern: 64 rows per block-pass (8 waves x 8 rows)
    for (int base = blockIdx.x * 64 + wave * 8; base < NNODES; base += 256 * 64) {
        float acc[8][HID];
        #pragma unroll
        for (int r = 0; r < 8; ++r)
            #pragma unroll
            for (int j = 0; j < HID; ++j) acc[r][j] = 0.f;

        for (int it = 0; it < 23; ++it) {
            const int k = lane + it * 64;   // k <= 1471 < KP
            float xv[8];
            #pragma unroll
            for (int r = 0; r < 8; ++r) {
                const int row = base + r;
                xv[r] = (row < NNODES && k < KF) ? x[(size_t)row * KF + k] : 0.f;
            }
            #pragma unroll
            for (int j = 0; j < HID; ++j) {
                const float wv = w1t[j * KP + k];   // zero-filled beyond KF
                #pragma unroll
                for (int r = 0; r < 8; ++r) acc[r][j] += xv[r] * wv;
            }
        }

        // Halving transpose-reduce: 16 vals x 64 lanes -> lane jout holds col sum
        #pragma unroll
        for (int r = 0; r < 8; ++r) {
            const int row = base + r;
            float v[HID];
            #pragma unroll
            for (int j = 0; j < HID; ++j) v[j] = acc[r][j];
            #pragma unroll
            for (int s = 0; s < 4; ++s) {
                const int d    = 1 << s;
                const int half = 8 >> s;
                const int sel  = (lane >> s) & 1;
                #pragma unroll
                for (int m = 0; m < half; ++m) {
                    const float send = sel ? v[m] : v[m + half];
                    const float keep = sel ? v[m + half] : v[m];
                    v[m] = keep + __shfl_xor(send, d);
                }
            }
            float t = v[0];
            t += __shfl_xor(t, 16);
            t += __shfl_xor(t, 32);
            if (row < NNODES && lane < HID) {
                const size_t o = (size_t)row * HID + jout;
                y[o]   = t;
                agg[o] = co * t;   // (1+eps)*y folded in; scatter adds on top
            }
        }
    }
}

// ---------------------------------------------------------------------------
// Kernel B: agg[dst] += y[src]  (thread per (edge, j))
// ---------------------------------------------------------------------------
__global__ __launch_bounds__(256) void scatter_add(const int* __restrict__ ei,
                                                   const float* __restrict__ y,
                                                   float* __restrict__ agg) {
    const int t = blockIdx.x * 256 + threadIdx.x;
    const int e = t >> 4;
    const int j = t & 15;
    if (e < NEDGES) {
        const int s = ei[e];           // src
        const int d = ei[NEDGES + e];  // dst
        atomicAdd(agg + d * HID + j, y[s * HID + j]);
    }
}

// ---------------------------------------------------------------------------
// Kernel C: out = sigmoid(relu(agg + b1) @ w2 + b2)   (agg already has eps term)
// ---------------------------------------------------------------------------
__global__ __launch_bounds__(256) void mlp_tail(const float* __restrict__ agg,
                                                const float* __restrict__ b1,
                                                const float* __restrict__ w2,
                                                const float* __restrict__ b2,
                                                float* __restrict__ out) {
    __shared__ float sw2[HID * NC];
    __shared__ float sb1[HID];
    __shared__ float sb2[NC];

    const int t = threadIdx.x;
    if (t < HID * NC) sw2[t] = w2[t];
    if (t < HID)      sb1[t] = b1[t];
    if (t < NC)       sb2[t] = b2[t];
    __syncthreads();

    const int i = blockIdx.x * 256 + t;
    if (i >= NNODES) return;

    const float4* a4 = (const float4*)(agg + (size_t)i * HID);

    float h[HID];
    #pragma unroll
    for (int q = 0; q < 4; ++q) {
        const float4 av = a4[q];
        h[q * 4 + 0] = fmaxf(av.x + sb1[q * 4 + 0], 0.f);
        h[q * 4 + 1] = fmaxf(av.y + sb1[q * 4 + 1], 0.f);
        h[q * 4 + 2] = fmaxf(av.z + sb1[q * 4 + 2], 0.f);
        h[q * 4 + 3] = fmaxf(av.w + sb1[q * 4 + 3], 0.f);
    }

    #pragma unroll
    for (int c = 0; c < NC; ++c) {
        float s = sb2[c];
        #pragma unroll
        for (int j = 0; j < HID; ++j) s += h[j] * sw2[j * NC + c];
        out[(size_t)i * NC + c] = 1.f / (1.f + __expf(-s));
    }
}

// ---------------------------------------------------------------------------
extern "C" void kernel_launch(void* const* d_in, const int* in_sizes, int n_in,
                              void* d_out, int out_size, void* d_ws, size_t ws_size,
                              hipStream_t stream) {
    const float* x   = (const float*)d_in[0];
    const int*   ei  = (const int*)d_in[1];
    const float* w1  = (const float*)d_in[2];
    const float* b1  = (const float*)d_in[3];
    const float* w2  = (const float*)d_in[4];
    const float* b2  = (const float*)d_in[5];
    const float* eps = (const float*)d_in[6];
    float* out = (float*)d_out;

    const size_t NY = (size_t)NNODES * HID;
    float* y   = (float*)d_ws;   // 6.4 MB
    float* agg = y + NY;         // 6.4 MB

    gemm_xw1<<<256, 512, 0, stream>>>(x, w1, eps, y, agg);
    scatter_add<<<(NEDGES * 16 + 255) / 256, 256, 0, stream>>>(ei, y, agg);
    mlp_tail<<<(NNODES + 255) / 256, 256, 0, stream>>>(agg, b1, w2, b2, out);
}